// Round 5
// baseline (34230.807 us; speedup 1.0000x reference)
//
#include <hip/hip_runtime.h>
#include <stdint.h>

// Problem constants (setup_inputs: B,L,D,H,A = 128,256,128,256,128)
#define LL   256
#define BB   128
#define DD   128
#define HH   256
#define H2C  512
#define H3C  768
#define ADIM 128
#define NCAT 896          // 768 (W) + 128 (W_action_1) concatenated columns
#define NU   640          // 512 (U[:, :2H]) + 128 (Ua1) cached-matvec columns
#define MROWS 32768       // L*B
#define EPSV 1e-5f

typedef __attribute__((ext_vector_type(8))) short short8;   // 8 bf16 (4 VGPRs)
typedef __attribute__((ext_vector_type(4))) float f32x4;
typedef unsigned short u16;

__device__ __forceinline__ u16 f2bf(float f) {
    unsigned int u = __float_as_uint(f);
    u = (u + 0x7FFFu + ((u >> 16) & 1u)) >> 16;   // RNE bf16 (finite data only)
    return (u16)u;
}
__device__ __forceinline__ float bf2f(u16 h) {
    return __uint_as_float(((unsigned int)h) << 16);
}
__device__ __forceinline__ float hsg(float x) {   // hard_sigmoid
    return fminf(fmaxf(0.2f * x + 0.5f, 0.f), 1.f);
}

// ---------------------------------------------------------------- small init
__global__ void init_flags(int* flags) {
    int i = threadIdx.x;
    if (i < 8) flags[i] = 0;      // done[0..3], anyb[0..3]
}

__global__ void build_bcat(const float* __restrict__ b_, const float* __restrict__ ba1,
                           float* __restrict__ bcat) {
    int i = blockIdx.x * 256 + threadIdx.x;
    if (i < NCAT) bcat[i] = (i < H3C) ? b_[i] : ba1[i - H3C];
}

// dmcur = mask.T ; apcur = 0 ; eos[t][b] = dm0[t][b] * (1 - dm0[t+1][b])
__global__ void init_seq(const float* __restrict__ mask, float* __restrict__ apcur,
                         float* __restrict__ dmcur, float* __restrict__ eosb) {
    int i = blockIdx.x * 256 + threadIdx.x;    // over L*B
    if (i >= MROWS) return;
    int t = i >> 7, b = i & 127;
    float dm  = mask[b * LL + t];
    float nxt = (t < LL - 1) ? mask[b * LL + t + 1] : 0.f;
    dmcur[i] = dm;
    apcur[i] = 0.f;
    eosb[i]  = dm * (1.f - nxt);
}

// ---------------------------------------------------------------- weight conversions
// Wcat = [W | W_action_1] (256 x 896), stored TRANSPOSED [c][k] for MFMA B-frags
__global__ void conv_wcatT(const float* __restrict__ W, const float* __restrict__ Wa1,
                           u16* __restrict__ hi, u16* __restrict__ lo) {
    int i = blockIdx.x * 256 + threadIdx.x;   // over NCAT*HH
    if (i >= NCAT * HH) return;
    int c = i / HH, k = i % HH;
    float v = (c < H3C) ? W[k * H3C + c] : Wa1[k * ADIM + (c - H3C)];
    u16 h = f2bf(v);
    hi[i] = h;
    lo[i] = f2bf(v - bf2f(h));
}

// Ucat = [U[:, :512] | Ua1] (256 x 640), TRANSPOSED [c][k]
__global__ void conv_ucatT(const float* __restrict__ U, const float* __restrict__ Ua1,
                           u16* __restrict__ hi, u16* __restrict__ lo) {
    int i = blockIdx.x * 256 + threadIdx.x;   // over NU*HH
    if (i >= NU * HH) return;
    int c = i / HH, k = i % HH;
    float v = (c < H2C) ? U[k * H3C + c] : Ua1[k * ADIM + (c - H2C)];
    u16 h = f2bf(v);
    hi[i] = h;
    lo[i] = f2bf(v - bf2f(h));
}

// W_emb (128 x 256) transposed -> [c][k], K=128
__global__ void conv_wembT(const float* __restrict__ We,
                           u16* __restrict__ hi, u16* __restrict__ lo) {
    int i = blockIdx.x * 256 + threadIdx.x;   // over HH*DD
    if (i >= HH * DD) return;
    int c = i / DD, k = i % DD;
    float v = We[k * HH + c];
    u16 h = f2bf(v);
    hi[i] = h;
    lo[i] = f2bf(v - bf2f(h));
}

// ---------------------------------------------------------------- split-bf16 MFMA GEMM
// C[M,N] = A[M,K]*B[K,N]; A is f32 row-major (hi/lo split happens during LDS
// staging), B is precomputed TRANSPOSED [N][K] hi/lo bf16. 3-MFMA split ~ f32.
__global__ __launch_bounds__(256)
void gemm_af32(const float* __restrict__ Af,
               const u16* __restrict__ Bhi, const u16* __restrict__ Blo,
               float* __restrict__ C, int Ni, int Ki,
               const float* __restrict__ bias, int remap, const int* __restrict__ skip)
{
    if (skip && *skip) return;
    __shared__ __attribute__((aligned(16))) u16 sA[2][128 * 32];  // [hi/lo][m][k]
    __shared__ __attribute__((aligned(16))) u16 sB[2][128 * 32];  // [hi/lo][n][k]
    const int tid = threadIdx.x, lane = tid & 63, wave = tid >> 6;
    const int bm = blockIdx.y * 128, bn = blockIdx.x * 128;
    const int wm = (wave >> 1) * 64, wn = (wave & 1) * 64;
    f32x4 acc[4][4] = {};
    for (int kk = 0; kk < Ki; kk += 32) {
        __syncthreads();
        #pragma unroll
        for (int j = 0; j < 2; ++j) {
            int cidx = tid + j * 256;                     // 0..511 8-elem chunks
            int r = cidx >> 2, kc = (cidx & 3) << 3;
            const float* ap = &Af[(size_t)(bm + r) * Ki + kk + kc];
            float4 f0 = *(const float4*)ap;
            float4 f1 = *(const float4*)(ap + 4);
            short8 hi8, lo8;
            #pragma unroll
            for (int e = 0; e < 4; ++e) {
                float v = (&f0.x)[e];
                u16 h = f2bf(v);
                hi8[e] = (short)h; lo8[e] = (short)f2bf(v - bf2f(h));
            }
            #pragma unroll
            for (int e = 0; e < 4; ++e) {
                float v = (&f1.x)[e];
                u16 h = f2bf(v);
                hi8[4 + e] = (short)h; lo8[4 + e] = (short)f2bf(v - bf2f(h));
            }
            *(short8*)&sA[0][cidx * 8] = hi8;
            *(short8*)&sA[1][cidx * 8] = lo8;
            *(uint4*)&sB[0][cidx * 8] = *(const uint4*)&Bhi[(size_t)(bn + r) * Ki + kk + kc];
            *(uint4*)&sB[1][cidx * 8] = *(const uint4*)&Blo[(size_t)(bn + r) * Ki + kk + kc];
        }
        __syncthreads();
        short8 a0[4], a1[4], b0[4], b1[4];
        int k8 = (lane >> 4) << 3;
        #pragma unroll
        for (int i = 0; i < 4; ++i) {
            int rA = wm + i * 16 + (lane & 15);
            a0[i] = *(short8*)&sA[0][rA * 32 + k8];
            a1[i] = *(short8*)&sA[1][rA * 32 + k8];
            int rB = wn + i * 16 + (lane & 15);
            b0[i] = *(short8*)&sB[0][rB * 32 + k8];
            b1[i] = *(short8*)&sB[1][rB * 32 + k8];
        }
        #pragma unroll
        for (int i = 0; i < 4; ++i)
        #pragma unroll
        for (int j = 0; j < 4; ++j) {
            acc[i][j] = __builtin_amdgcn_mfma_f32_16x16x32_bf16(a0[i], b0[j], acc[i][j], 0, 0, 0);
            acc[i][j] = __builtin_amdgcn_mfma_f32_16x16x32_bf16(a0[i], b1[j], acc[i][j], 0, 0, 0);
            acc[i][j] = __builtin_amdgcn_mfma_f32_16x16x32_bf16(a1[i], b0[j], acc[i][j], 0, 0, 0);
        }
    }
    int r4 = (lane >> 4) << 2, cl = lane & 15;
    #pragma unroll
    for (int i = 0; i < 4; ++i)
    #pragma unroll
    for (int j = 0; j < 4; ++j)
    #pragma unroll
    for (int q = 0; q < 4; ++q) {
        int row = bm + wm + i * 16 + r4 + q;
        int col = bn + wn + j * 16 + cl;
        float v = acc[i][j][q];
        if (bias) v += bias[col];
        if (remap) {   // embed: A-rows are (b,l); write to xh[(t*B + b)]
            int b_ = row >> 8, t_ = row & 255;
            C[(size_t)(t_ * BB + b_) * Ni + col] = v;
        } else {
            C[(size_t)row * Ni + col] = v;
        }
    }
}

// ---------------------------------------------------------------- row LN (in place on raw)
__global__ __launch_bounds__(256)
void ln_rows(float* __restrict__ raw, const float* __restrict__ bcat,
             const float* __restrict__ gam, const float* __restrict__ bet,
             const int* __restrict__ skip)
{
    if (skip && *skip) return;
    int wave = threadIdx.x >> 6, lane = threadIdx.x & 63;
    size_t row = (size_t)blockIdx.x * 4 + wave;
    float* base = raw + row * NCAT;
    float v[14];
    #pragma unroll
    for (int j = 0; j < 14; ++j) v[j] = base[lane + j * 64] + bcat[lane + j * 64];
    float s = 0.f;
    #pragma unroll
    for (int j = 0; j < 12; ++j) s += v[j];
    #pragma unroll
    for (int o = 32; o; o >>= 1) s += __shfl_down(s, o);
    s = __shfl(s, 0);
    float mean = s / 768.f;
    float q = 0.f;
    #pragma unroll
    for (int j = 0; j < 12; ++j) { float d = v[j] - mean; q += d * d; }
    #pragma unroll
    for (int o = 32; o; o >>= 1) q += __shfl_down(q, o);
    q = __shfl(q, 0);
    float inv = 1.f / (sqrtf(q / 768.f + EPSV) + EPSV);
    #pragma unroll
    for (int j = 0; j < 12; ++j) {
        int c = lane + j * 64;
        base[c] = gam[c] * ((v[j] - mean) * inv) + bet[c];
    }
    #pragma unroll
    for (int j = 12; j < 14; ++j) base[lane + j * 64] = v[j];
}

// ---------------------------------------------------------------- sparse scan
// 128 WGs x 1 batch, 640 threads. Caches m1aa = h @ [U[:,:512] | Ua1] in LDS.
// Per step: logits from cached aa -> action -> case code:
//   0 keep (dm=0 or h_only) : nothing
//   1 copy (x_only)         : h=x_t, m1aa=XU row (precomputed GEMM)
//   2 zero                  : h=0, m1aa=0
//   3 both                  : full h_cand pipeline + fresh m1aa matvec (only case
//                             that streams U from L2)
// xh is read (x_t at row t+1, prefetched) and written IN PLACE (h at row t).
__global__ __launch_bounds__(640, 1)
void scan_sparse(const float* __restrict__ raw,     // [MROWS][896] s1(LN'd)|xa
                 float* __restrict__ xh,            // [MROWS][256] x in, h out
                 const float* __restrict__ XU,      // [MROWS][640] = x @ [U12|Ua1]
                 const float* __restrict__ apcur,   // [L*B]
                 const float* __restrict__ dmcur,
                 const float* __restrict__ eosb,
                 float* __restrict__ aseq,
                 float* __restrict__ dmseq,
                 const float* __restrict__ U,       // [256][768]
                 const float* __restrict__ Ua1,     // [256][128]
                 const float* __restrict__ W2,      // [128][2]
                 const float* __restrict__ b2g,     // [2]
                 const float* __restrict__ gam,     // [2][768]
                 const float* __restrict__ bet,
                 int llm, int* __restrict__ anyb, const int* __restrict__ skip)
{
    if (skip && *skip) return;
    __shared__ __attribute__((aligned(16))) float h_s[HH], z_s[HH], rh_s[HH];
    __shared__ float m1aa[NU];
    __shared__ float pm[H2C], red[32];
    __shared__ float g1v[H2C], be1v[H2C], g2v[HH], be2v[HH], w2l[2 * ADIM];
    __shared__ int code_s;
    const int tid = threadIdx.x, lane = tid & 63, wv = tid >> 6;
    const int b = blockIdx.x;

    for (int i = tid; i < H2C; i += 640) { g1v[i] = gam[H3C + i]; be1v[i] = bet[H3C + i]; }
    for (int i = tid; i < HH; i += 640)  { g2v[i] = gam[H3C + H2C + i]; be2v[i] = bet[H3C + H2C + i]; }
    for (int i = tid; i < 2 * ADIM; i += 640) w2l[i] = W2[i];
    if (tid < HH) h_s[tid] = 0.f;
    m1aa[tid] = 0.f;
    float a_tm1 = 0.f, dm_tm1 = 0.f, b20 = 0.f, b21 = 0.f;   // tid 0 state
    if (tid == 0) { b20 = b2g[0]; b21 = b2g[1]; }
    int anyLocal = 0;

    // prologue prefetch (t = 0)
    float s1_c = 0.f, s1t_c = 0.f, xt_c = 0.f, xu_c = 0.f, xa0_c = 0.f, xa1_c = 0.f;
    float ap_c = 0.f, dm_c = 0.f, sdm_c = 1.f, sem_c = 0.f;
    {
        const float* rp = raw + (size_t)b * NCAT;
        if (tid < H2C) s1_c = rp[tid];
        if (tid < HH) { s1t_c = rp[H2C + tid]; xt_c = xh[(size_t)b * HH + tid]; }
        xu_c = XU[(size_t)b * NU + tid];
        if (wv == 0) { xa0_c = rp[H3C + lane]; xa1_c = rp[H3C + 64 + lane]; }
        if (tid == 0) { ap_c = apcur[b]; dm_c = dmcur[b]; }
    }
    __syncthreads();

    for (int t = 0; t < LL; ++t) {
        const int rowc = t * BB + b;
        const int rowN = (t < LL - 1 ? t + 1 : t) * BB + b;
        // issue next-step prefetch (row t+1 of xh still holds x: h[t] not yet written)
        float s1_n = 0.f, s1t_n = 0.f, xt_n = 0.f, xu_n = 0.f, xa0_n = 0.f, xa1_n = 0.f;
        float ap_n = 0.f, dm_n = 0.f, sdm_n = 0.f, sem_n = 0.f;
        {
            const float* rp = raw + (size_t)rowN * NCAT;
            if (tid < H2C) s1_n = rp[tid];
            if (tid < HH) { s1t_n = rp[H2C + tid]; xt_n = xh[(size_t)rowN * HH + tid]; }
            xu_n = XU[(size_t)rowN * NU + tid];
            if (wv == 0) { xa0_n = rp[H3C + lane]; xa1_n = rp[H3C + 64 + lane]; }
            if (tid == 0) { ap_n = apcur[rowN]; dm_n = dmcur[rowN];
                            sdm_n = dmcur[rowc]; sem_n = eosb[rowc]; }
        }

        // ---- P0: action logits from cached aa (wave 0); gate logic on tid 0
        if (wv == 0) {
            float v0 = fmaxf(xa0_c + m1aa[H2C + lane], 0.f);
            float v1 = fmaxf(xa1_c + m1aa[H2C + 64 + lane], 0.f);
            float l0 = v0 * w2l[lane * 2]     + v1 * w2l[(64 + lane) * 2];
            float l1 = v0 * w2l[lane * 2 + 1] + v1 * w2l[(64 + lane) * 2 + 1];
            #pragma unroll
            for (int o = 32; o; o >>= 1) { l0 += __shfl_down(l0, o); l1 += __shfl_down(l1, o); }
            if (lane == 0) {
                float p0 = fminf(expf(l0 + b20), 1000.f);
                float p1 = fminf(expf(l1 + b21), 1000.f);
                float act = (p0 <= p1) ? 1.f : 0.f;
                if (ap_c  > 0.f) act = 1.f;
                if (llm   > 0)   act = 1.f;
                if (sem_c > 0.f) act = 0.f;
                float both   = (1.f - ap_c) * dm_c * act * dm_tm1;
                float h_only = dm_tm1 * act * (ap_c + (1.f - ap_c) * (1.f - dm_c));
                float x_only = dm_c * (1.f - ap_c) * (1.f - act + act * (1.f - dm_tm1));
                float dmnew  = both + x_only + h_only;
                float a_out  = (sdm_c > 0.f) ? act : a_tm1;
                aseq[rowc] = a_out; dmseq[rowc] = dmnew;
                a_tm1 = a_out; dm_tm1 = dmnew;
                anyLocal |= (both > 0.f) ? 1 : 0;
                int cd;
                if (dm_c <= 0.f)       cd = 0;   // h kept (dm override)
                else if (both > 0.f)   cd = 3;   // full update
                else if (h_only > 0.f) cd = 0;   // h kept
                else if (x_only > 0.f) cd = 1;   // h = x_t
                else                   cd = 2;   // h = 0
                code_s = cd;
            }
        }
        __syncthreads();   // B1
        int cd = code_s;

        if (cd == 3) {
            // ---- m1 LN stats from cache
            if (tid < H2C) {
                float v = m1aa[tid];
                float s = v, q = v * v;
                #pragma unroll
                for (int o = 32; o; o >>= 1) { s += __shfl_down(s, o); q += __shfl_down(q, o); }
                if (lane == 0) { red[wv * 2] = s; red[wv * 2 + 1] = q; }
            }
            __syncthreads();   // B2
            if (tid < H2C) {
                float ss = 0.f, qs = 0.f;
                #pragma unroll
                for (int w8 = 0; w8 < 8; ++w8) { ss += red[w8 * 2]; qs += red[w8 * 2 + 1]; }
                float mean = ss * (1.f / 512.f);
                float var  = qs * (1.f / 512.f) - mean * mean;
                float inv  = 1.f / (sqrtf(var + EPSV) + EPSV);
                float s2 = g1v[tid] * ((m1aa[tid] - mean) * inv) + be1v[tid];
                float gate = hsg(s1_c + s2);
                if (tid < HH) z_s[tid] = gate;
                else          rh_s[tid - HH] = gate * h_s[tid - HH];
            }
            __syncthreads();   // B3
            // ---- m2 = rh @ U[:,512:768], split-K by 2
            if (tid < H2C) {
                int c = tid & (HH - 1), half = tid >> 8;
                const float* ucol = U + (size_t)(half * 128) * H3C + H2C + c;
                const float* rh = rh_s + half * 128;
                float a0 = 0.f, a1 = 0.f, a2 = 0.f, a3 = 0.f;
                for (int k = 0; k < 128; k += 8) {
                    float4 r0 = *(const float4*)&rh[k];
                    float4 r1 = *(const float4*)&rh[k + 4];
                    a0 = fmaf(ucol[(size_t)(k + 0) * H3C], r0.x, a0);
                    a1 = fmaf(ucol[(size_t)(k + 1) * H3C], r0.y, a1);
                    a2 = fmaf(ucol[(size_t)(k + 2) * H3C], r0.z, a2);
                    a3 = fmaf(ucol[(size_t)(k + 3) * H3C], r0.w, a3);
                    a0 = fmaf(ucol[(size_t)(k + 4) * H3C], r1.x, a0);
                    a1 = fmaf(ucol[(size_t)(k + 5) * H3C], r1.y, a1);
                    a2 = fmaf(ucol[(size_t)(k + 6) * H3C], r1.z, a2);
                    a3 = fmaf(ucol[(size_t)(k + 7) * H3C], r1.w, a3);
                }
                pm[tid] = (a0 + a1) + (a2 + a3);
            }
            __syncthreads();   // B4
            float m2v = 0.f;
            if (tid < HH) {
                m2v = pm[tid] + pm[tid + HH];
                float s = m2v, q = m2v * m2v;
                #pragma unroll
                for (int o = 32; o; o >>= 1) { s += __shfl_down(s, o); q += __shfl_down(q, o); }
                if (lane == 0) { red[wv * 2] = s; red[wv * 2 + 1] = q; }
            }
            __syncthreads();   // B5
            if (tid < HH) {
                float ss = 0.f, qs = 0.f;
                #pragma unroll
                for (int w4 = 0; w4 < 4; ++w4) { ss += red[w4 * 2]; qs += red[w4 * 2 + 1]; }
                float mean = ss * (1.f / 256.f);
                float var  = qs * (1.f / 256.f) - mean * mean;
                float inv  = 1.f / (sqrtf(var + EPSV) + EPSV);
                float ln2 = g2v[tid] * ((m2v - mean) * inv) + be2v[tid];
                float tc = tanhf(s1t_c + ln2);
                float zv = z_s[tid];
                float hc = zv * h_s[tid] + (1.f - zv) * tc;
                h_s[tid] = hc;
                xh[(size_t)rowc * HH + tid] = hc;
            }
            __syncthreads();   // B6 (new h visible)
            // ---- refresh cache: m1aa = h @ [U12 | Ua1]
            {
                float a0 = 0.f, a1 = 0.f, a2 = 0.f, a3 = 0.f;
                if (tid < H2C) {
                    const float* wc = U + tid;
                    for (int k = 0; k < HH; k += 8) {
                        float4 h0 = *(const float4*)&h_s[k];
                        float4 h1 = *(const float4*)&h_s[k + 4];
                        a0 = fmaf(wc[(size_t)(k + 0) * H3C], h0.x, a0);
                        a1 = fmaf(wc[(size_t)(k + 1) * H3C], h0.y, a1);
                        a2 = fmaf(wc[(size_t)(k + 2) * H3C], h0.z, a2);
                        a3 = fmaf(wc[(size_t)(k + 3) * H3C], h0.w, a3);
                        a0 = fmaf(wc[(size_t)(k + 4) * H3C], h1.x, a0);
                        a1 = fmaf(wc[(size_t)(k + 5) * H3C], h1.y, a1);
                        a2 = fmaf(wc[(size_t)(k + 6) * H3C], h1.z, a2);
                        a3 = fmaf(wc[(size_t)(k + 7) * H3C], h1.w, a3);
                    }
                } else {
                    const float* wc = Ua1 + (tid - H2C);
                    for (int k = 0; k < HH; k += 8) {
                        float4 h0 = *(const float4*)&h_s[k];
                        float4 h1 = *(const float4*)&h_s[k + 4];
                        a0 = fmaf(wc[(size_t)(k + 0) * ADIM], h0.x, a0);
                        a1 = fmaf(wc[(size_t)(k + 1) * ADIM], h0.y, a1);
                        a2 = fmaf(wc[(size_t)(k + 2) * ADIM], h0.z, a2);
                        a3 = fmaf(wc[(size_t)(k + 3) * ADIM], h0.w, a3);
                        a0 = fmaf(wc[(size_t)(k + 4) * ADIM], h1.x, a0);
                        a1 = fmaf(wc[(size_t)(k + 5) * ADIM], h1.y, a1);
                        a2 = fmaf(wc[(size_t)(k + 6) * ADIM], h1.z, a2);
                        a3 = fmaf(wc[(size_t)(k + 7) * ADIM], h1.w, a3);
                    }
                }
                m1aa[tid] = (a0 + a1) + (a2 + a3);
            }
            __syncthreads();   // B7 (cache ready for next P0)
        } else {
            if (cd == 1) {            // h = x_t, cache = precomputed XU row
                if (tid < HH) h_s[tid] = xt_c;
                m1aa[tid] = xu_c;
            } else if (cd == 2) {     // h = 0
                if (tid < HH) h_s[tid] = 0.f;
                m1aa[tid] = 0.f;
            }
            __syncthreads();   // Bend
            if (tid < HH) xh[(size_t)rowc * HH + tid] = h_s[tid];
        }

        // rotate prefetch regs
        s1_c = s1_n; s1t_c = s1t_n; xt_c = xt_n; xu_c = xu_n;
        xa0_c = xa0_n; xa1_c = xa1_n;
        ap_c = ap_n; dm_c = dm_n; sdm_c = sdm_n; sem_c = sem_n;
    }
    if (tid == 0 && anyLocal) atomicOr(anyb, 1);
}

// ---------------------------------------------------------------- commit (vstep glue)
// xh already holds h in place; only masks/flags to update.
__global__ void commit_pass(float* __restrict__ apcur, const float* __restrict__ aseq,
                            float* __restrict__ dmcur, const float* __restrict__ dmseq,
                            const int* __restrict__ donep, int* __restrict__ donep1,
                            const int* __restrict__ anyb)
{
    int i = blockIdx.x * 256 + threadIdx.x;   // over MROWS
    int done = *donep;
    if (blockIdx.x == 0 && threadIdx.x == 0)
        *donep1 = done | ((*anyb == 0) ? 1 : 0);
    if (done || i >= MROWS) return;
    int t = i >> 7;
    apcur[i] = (t < LL - 1) ? aseq[i + BB] : 0.f;
    dmcur[i] = dmseq[i];
}

__global__ void write_out(const float* __restrict__ xh, float* __restrict__ outp) {
    int i = blockIdx.x * 256 + threadIdx.x;   // 32768 = B*H
    if (i >= BB * HH) return;
    int b = i >> 8, h = i & 255;
    outp[i] = xh[((size_t)(LL - 1) * BB + b) * HH + h];
}

// ---------------------------------------------------------------- launcher
static inline size_t alignUp(size_t v) { return (v + 255) & ~(size_t)255; }

extern "C" void kernel_launch(void* const* d_in, const int* in_sizes, int n_in,
                              void* d_out, int out_size, void* d_ws, size_t ws_size,
                              hipStream_t stream) {
    (void)in_sizes; (void)n_in; (void)out_size; (void)ws_size;
    const float* x     = (const float*)d_in[0];
    const float* mask  = (const float*)d_in[1];
    const float* W_emb = (const float*)d_in[3];
    const float* b_emb = (const float*)d_in[4];
    const float* W     = (const float*)d_in[5];
    const float* U     = (const float*)d_in[6];
    const float* bvec  = (const float*)d_in[7];
    const float* Wa1   = (const float*)d_in[8];
    const float* Ua1   = (const float*)d_in[9];
    const float* ba1   = (const float*)d_in[10];
    const float* W2    = (const float*)d_in[11];
    const float* b2    = (const float*)d_in[12];
    const float* gam   = (const float*)d_in[13];
    const float* bet   = (const float*)d_in[14];
    float* outp = (float*)d_out;

    // workspace budget: raw 117.4 + XU 83.9 + xh 33.5 + weights ~1.8 MB = ~237 MB
    char* ws = (char*)d_ws;
    size_t off = 0;
    auto take = [&](size_t bytes) { char* p = ws + off; off = alignUp(off + bytes); return p; };
    float* raw  = (float*)take((size_t)MROWS * NCAT * 4);     // 117.4 MB
    float* XU   = (float*)take((size_t)MROWS * NU * 4);       // 83.9 MB
    float* xh   = (float*)take((size_t)MROWS * HH * 4);       // 33.5 MB (x in / h out)
    u16* WcT_hi = (u16*)take((size_t)NCAT * HH * 2);
    u16* WcT_lo = (u16*)take((size_t)NCAT * HH * 2);
    u16* UcT_hi = (u16*)take((size_t)NU * HH * 2);
    u16* UcT_lo = (u16*)take((size_t)NU * HH * 2);
    u16* WeT_hi = (u16*)take((size_t)HH * DD * 2);
    u16* WeT_lo = (u16*)take((size_t)HH * DD * 2);
    float* apcur = (float*)take((size_t)MROWS * 4);
    float* dmcur = (float*)take((size_t)MROWS * 4);
    float* eosb  = (float*)take((size_t)MROWS * 4);
    float* aseq  = (float*)take((size_t)MROWS * 4);
    float* dmseq = (float*)take((size_t)MROWS * 4);
    float* bcat  = (float*)take((size_t)NCAT * 4);
    int* flags   = (int*)take(64);
    int* done = flags;        // done[0..3]
    int* anyb = flags + 4;    // anyb[0..3]

    init_flags<<<1, 64, 0, stream>>>(flags);
    build_bcat<<<4, 256, 0, stream>>>(bvec, ba1, bcat);
    conv_wcatT<<<(NCAT * HH + 255) / 256, 256, 0, stream>>>(W, Wa1, WcT_hi, WcT_lo);
    conv_ucatT<<<(NU * HH + 255) / 256, 256, 0, stream>>>(U, Ua1, UcT_hi, UcT_lo);
    conv_wembT<<<(HH * DD + 255) / 256, 256, 0, stream>>>(W_emb, WeT_hi, WeT_lo);
    init_seq<<<MROWS / 256, 256, 0, stream>>>(mask, apcur, dmcur, eosb);

    // embed: xh[(t,b)] = x[(b,l)] @ W_emb + b_emb   (A = f32 x, remap to [L][B])
    gemm_af32<<<dim3(HH / 128, MROWS / 128), 256, 0, stream>>>(
        x, WeT_hi, WeT_lo, xh, HH, DD, b_emb, 1, nullptr);

    for (int p = 0; p < 4; ++p) {
        const int* skip = (p == 1 || p == 2) ? &done[p] : nullptr;
        gemm_af32<<<dim3(NCAT / 128, MROWS / 128), 256, 0, stream>>>(
            xh, WcT_hi, WcT_lo, raw, NCAT, HH, nullptr, 0, skip);
        gemm_af32<<<dim3(NU / 128, MROWS / 128), 256, 0, stream>>>(
            xh, UcT_hi, UcT_lo, XU, NU, HH, nullptr, 0, skip);
        ln_rows<<<MROWS / 4, 256, 0, stream>>>(raw, bcat, gam, bet, skip);
        scan_sparse<<<BB, 640, 0, stream>>>(raw, xh, XU, apcur, dmcur, eosb,
                                            aseq, dmseq, U, Ua1, W2, b2, gam, bet,
                                            (p == 3) ? 1 : 0, &anyb[p], skip);
        if (p < 3)
            commit_pass<<<MROWS / 256, 256, 0, stream>>>(
                apcur, aseq, dmcur, dmseq, &done[p], &done[p + 1], &anyb[p]);
    }
    write_out<<<(BB * HH) / 256, 256, 0, stream>>>(xh, outp);
}

// Round 6
// 9607.376 us; speedup vs baseline: 3.5630x; 3.5630x over previous
//
#include <hip/hip_runtime.h>
#include <stdint.h>

// Problem constants (setup_inputs: B,L,D,H,A = 128,256,128,256,128)
#define LL   256
#define BB   128
#define DD   128
#define HH   256
#define H2C  512
#define H3C  768
#define ADIM 128
#define NCAT 896          // 768 (W) + 128 (W_action_1) concatenated columns
#define NU   640          // 512 (U[:, :2H]) + 128 (Ua1) cached-matvec columns
#define MROWS 32768       // L*B
#define EPSV 1e-5f

typedef __attribute__((ext_vector_type(8))) short short8;   // 8 bf16 (4 VGPRs)
typedef __attribute__((ext_vector_type(4))) float f32x4;
typedef unsigned short u16;

#define NTL(x) __builtin_nontemporal_load(&(x))

__device__ __forceinline__ u16 f2bf(float f) {
    unsigned int u = __float_as_uint(f);
    u = (u + 0x7FFFu + ((u >> 16) & 1u)) >> 16;   // RNE bf16 (finite data only)
    return (u16)u;
}
__device__ __forceinline__ float bf2f(u16 h) {
    return __uint_as_float(((unsigned int)h) << 16);
}
__device__ __forceinline__ float hsg(float x) {   // hard_sigmoid
    return fminf(fmaxf(0.2f * x + 0.5f, 0.f), 1.f);
}

// ---------------------------------------------------------------- small init
__global__ void init_flags(int* flags) {
    int i = threadIdx.x;
    if (i < 8) flags[i] = 0;      // done[0..3], anyb[0..3]
}

__global__ void build_bcat(const float* __restrict__ b_, const float* __restrict__ ba1,
                           float* __restrict__ bcat) {
    int i = blockIdx.x * 256 + threadIdx.x;
    if (i < NCAT) bcat[i] = (i < H3C) ? b_[i] : ba1[i - H3C];
}

// dmcur = mask.T ; apcur = 0 ; eos[t][b] = dm0[t][b] * (1 - dm0[t+1][b])
__global__ void init_seq(const float* __restrict__ mask, float* __restrict__ apcur,
                         float* __restrict__ dmcur, float* __restrict__ eosb) {
    int i = blockIdx.x * 256 + threadIdx.x;    // over L*B
    if (i >= MROWS) return;
    int t = i >> 7, b = i & 127;
    float dm  = mask[b * LL + t];
    float nxt = (t < LL - 1) ? mask[b * LL + t + 1] : 0.f;
    dmcur[i] = dm;
    apcur[i] = 0.f;
    eosb[i]  = dm * (1.f - nxt);
}

// ---------------------------------------------------------------- weight conversions
// Wcat = [W | W_action_1] (256 x 896), stored TRANSPOSED [c][k] for MFMA B-frags
__global__ void conv_wcatT(const float* __restrict__ W, const float* __restrict__ Wa1,
                           u16* __restrict__ hi, u16* __restrict__ lo) {
    int i = blockIdx.x * 256 + threadIdx.x;   // over NCAT*HH
    if (i >= NCAT * HH) return;
    int c = i / HH, k = i % HH;
    float v = (c < H3C) ? W[k * H3C + c] : Wa1[k * ADIM + (c - H3C)];
    u16 h = f2bf(v);
    hi[i] = h;
    lo[i] = f2bf(v - bf2f(h));
}

// Ucat = [U[:, :512] | Ua1] (256 x 640), TRANSPOSED [c][k] (bf16 hi/lo, for XU GEMM)
__global__ void conv_ucatT(const float* __restrict__ U, const float* __restrict__ Ua1,
                           u16* __restrict__ hi, u16* __restrict__ lo) {
    int i = blockIdx.x * 256 + threadIdx.x;   // over NU*HH
    if (i >= NU * HH) return;
    int c = i / HH, k = i % HH;
    float v = (c < H2C) ? U[k * H3C + c] : Ua1[k * ADIM + (c - H2C)];
    u16 h = f2bf(v);
    hi[i] = h;
    lo[i] = f2bf(v - bf2f(h));
}

// f32 TRANSPOSED copies for the scan's per-thread contiguous matvec rows:
//   UT12a[c][k], c<512: U[k][c]; c>=512: Ua1[k][c-512]      (640 x 256)
//   UT3  [c][k] = U[k][512+c]                               (256 x 256)
__global__ void conv_utT(const float* __restrict__ U, const float* __restrict__ Ua1,
                         float* __restrict__ UT12a, float* __restrict__ UT3) {
    int i = blockIdx.x * 256 + threadIdx.x;   // over (640+256)*256
    if (i >= (NU + HH) * HH) return;
    int c = i >> 8, k = i & 255;
    if (c < NU) {
        UT12a[(size_t)c * HH + k] = (c < H2C) ? U[(size_t)k * H3C + c]
                                              : Ua1[(size_t)k * ADIM + (c - H2C)];
    } else {
        int c3 = c - NU;
        UT3[(size_t)c3 * HH + k] = U[(size_t)k * H3C + H2C + c3];
    }
}

// W_emb (128 x 256) transposed -> [c][k], K=128
__global__ void conv_wembT(const float* __restrict__ We,
                           u16* __restrict__ hi, u16* __restrict__ lo) {
    int i = blockIdx.x * 256 + threadIdx.x;   // over HH*DD
    if (i >= HH * DD) return;
    int c = i / DD, k = i % DD;
    float v = We[k * HH + c];
    u16 h = f2bf(v);
    hi[i] = h;
    lo[i] = f2bf(v - bf2f(h));
}

// ---------------------------------------------------------------- split-bf16 MFMA GEMM
// C[M,N] = A[M,K]*B[K,N]; A is f32 row-major (hi/lo split during LDS staging),
// B is precomputed TRANSPOSED [N][K] hi/lo bf16. 3-MFMA split ~ f32.
__global__ __launch_bounds__(256)
void gemm_af32(const float* __restrict__ Af,
               const u16* __restrict__ Bhi, const u16* __restrict__ Blo,
               float* __restrict__ C, int Ni, int Ki,
               const float* __restrict__ bias, int remap, const int* __restrict__ skip)
{
    if (skip && *skip) return;
    __shared__ __attribute__((aligned(16))) u16 sA[2][128 * 32];  // [hi/lo][m][k]
    __shared__ __attribute__((aligned(16))) u16 sB[2][128 * 32];  // [hi/lo][n][k]
    const int tid = threadIdx.x, lane = tid & 63, wave = tid >> 6;
    const int bm = blockIdx.y * 128, bn = blockIdx.x * 128;
    const int wm = (wave >> 1) * 64, wn = (wave & 1) * 64;
    f32x4 acc[4][4] = {};
    for (int kk = 0; kk < Ki; kk += 32) {
        __syncthreads();
        #pragma unroll
        for (int j = 0; j < 2; ++j) {
            int cidx = tid + j * 256;                     // 0..511 8-elem chunks
            int r = cidx >> 2, kc = (cidx & 3) << 3;
            const float* ap = &Af[(size_t)(bm + r) * Ki + kk + kc];
            float4 f0 = *(const float4*)ap;
            float4 f1 = *(const float4*)(ap + 4);
            short8 hi8, lo8;
            #pragma unroll
            for (int e = 0; e < 4; ++e) {
                float v = (&f0.x)[e];
                u16 h = f2bf(v);
                hi8[e] = (short)h; lo8[e] = (short)f2bf(v - bf2f(h));
            }
            #pragma unroll
            for (int e = 0; e < 4; ++e) {
                float v = (&f1.x)[e];
                u16 h = f2bf(v);
                hi8[4 + e] = (short)h; lo8[4 + e] = (short)f2bf(v - bf2f(h));
            }
            *(short8*)&sA[0][cidx * 8] = hi8;
            *(short8*)&sA[1][cidx * 8] = lo8;
            *(uint4*)&sB[0][cidx * 8] = *(const uint4*)&Bhi[(size_t)(bn + r) * Ki + kk + kc];
            *(uint4*)&sB[1][cidx * 8] = *(const uint4*)&Blo[(size_t)(bn + r) * Ki + kk + kc];
        }
        __syncthreads();
        short8 a0[4], a1[4], b0[4], b1[4];
        int k8 = (lane >> 4) << 3;
        #pragma unroll
        for (int i = 0; i < 4; ++i) {
            int rA = wm + i * 16 + (lane & 15);
            a0[i] = *(short8*)&sA[0][rA * 32 + k8];
            a1[i] = *(short8*)&sA[1][rA * 32 + k8];
            int rB = wn + i * 16 + (lane & 15);
            b0[i] = *(short8*)&sB[0][rB * 32 + k8];
            b1[i] = *(short8*)&sB[1][rB * 32 + k8];
        }
        #pragma unroll
        for (int i = 0; i < 4; ++i)
        #pragma unroll
        for (int j = 0; j < 4; ++j) {
            acc[i][j] = __builtin_amdgcn_mfma_f32_16x16x32_bf16(a0[i], b0[j], acc[i][j], 0, 0, 0);
            acc[i][j] = __builtin_amdgcn_mfma_f32_16x16x32_bf16(a0[i], b1[j], acc[i][j], 0, 0, 0);
            acc[i][j] = __builtin_amdgcn_mfma_f32_16x16x32_bf16(a1[i], b0[j], acc[i][j], 0, 0, 0);
        }
    }
    int r4 = (lane >> 4) << 2, cl = lane & 15;
    #pragma unroll
    for (int i = 0; i < 4; ++i)
    #pragma unroll
    for (int j = 0; j < 4; ++j)
    #pragma unroll
    for (int q = 0; q < 4; ++q) {
        int row = bm + wm + i * 16 + r4 + q;
        int col = bn + wn + j * 16 + cl;
        float v = acc[i][j][q];
        if (bias) v += bias[col];
        if (remap) {   // embed: A-rows are (b,l); write to xh[(t*B + b)]
            int b_ = row >> 8, t_ = row & 255;
            C[(size_t)(t_ * BB + b_) * Ni + col] = v;
        } else {
            C[(size_t)row * Ni + col] = v;
        }
    }
}

// ---------------------------------------------------------------- row LN (in place on raw)
__global__ __launch_bounds__(256)
void ln_rows(float* __restrict__ raw, const float* __restrict__ bcat,
             const float* __restrict__ gam, const float* __restrict__ bet,
             const int* __restrict__ skip)
{
    if (skip && *skip) return;
    int wave = threadIdx.x >> 6, lane = threadIdx.x & 63;
    size_t row = (size_t)blockIdx.x * 4 + wave;
    float* base = raw + row * NCAT;
    float v[14];
    #pragma unroll
    for (int j = 0; j < 14; ++j) v[j] = base[lane + j * 64] + bcat[lane + j * 64];
    float s = 0.f;
    #pragma unroll
    for (int j = 0; j < 12; ++j) s += v[j];
    #pragma unroll
    for (int o = 32; o; o >>= 1) s += __shfl_down(s, o);
    s = __shfl(s, 0);
    float mean = s / 768.f;
    float q = 0.f;
    #pragma unroll
    for (int j = 0; j < 12; ++j) { float d = v[j] - mean; q += d * d; }
    #pragma unroll
    for (int o = 32; o; o >>= 1) q += __shfl_down(q, o);
    q = __shfl(q, 0);
    float inv = 1.f / (sqrtf(q / 768.f + EPSV) + EPSV);
    #pragma unroll
    for (int j = 0; j < 12; ++j) {
        int c = lane + j * 64;
        base[c] = gam[c] * ((v[j] - mean) * inv) + bet[c];
    }
    #pragma unroll
    for (int j = 12; j < 14; ++j) base[lane + j * 64] = v[j];
}

// ---------------------------------------------------------------- sparse scan
// 128 WGs x 1 batch, 640 threads. Caches m1aa = h @ [U[:,:512] | Ua1] in LDS.
// Case codes: 0 keep, 1 copy (XU row), 2 zero, 3 full update (the only case
// that streams weights — now from f32 TRANSPOSED UT12a/UT3, contiguous rows).
// Streaming reads (raw/XU/xh) are non-temporal to keep UT L2-resident.
__global__ __launch_bounds__(640, 1)
void scan_sparse(const float* __restrict__ raw,     // [MROWS][896] s1(LN'd)|xa
                 float* __restrict__ xh,            // [MROWS][256] x in, h out
                 const float* __restrict__ XU,      // [MROWS][640] = x @ [U12|Ua1]
                 const float* __restrict__ apcur,   // [L*B]
                 const float* __restrict__ dmcur,
                 const float* __restrict__ eosb,
                 float* __restrict__ aseq,
                 float* __restrict__ dmseq,
                 const float* __restrict__ UT12a,   // [640][256] transposed
                 const float* __restrict__ UT3,     // [256][256] transposed
                 const float* __restrict__ W2,      // [128][2]
                 const float* __restrict__ b2g,     // [2]
                 const float* __restrict__ gam,     // [2][768]
                 const float* __restrict__ bet,
                 int llm, int* __restrict__ anyb, const int* __restrict__ skip)
{
    if (skip && *skip) return;
    __shared__ __attribute__((aligned(16))) float h_s[HH], z_s[HH], rh_s[HH];
    __shared__ float m1aa[NU];
    __shared__ float pm[H2C], red[32];
    __shared__ float g1v[H2C], be1v[H2C], g2v[HH], be2v[HH], w2l[2 * ADIM];
    __shared__ int code_s;
    const int tid = threadIdx.x, lane = tid & 63, wv = tid >> 6;
    const int b = blockIdx.x;

    for (int i = tid; i < H2C; i += 640) { g1v[i] = gam[H3C + i]; be1v[i] = bet[H3C + i]; }
    for (int i = tid; i < HH; i += 640)  { g2v[i] = gam[H3C + H2C + i]; be2v[i] = bet[H3C + H2C + i]; }
    for (int i = tid; i < 2 * ADIM; i += 640) w2l[i] = W2[i];
    if (tid < HH) h_s[tid] = 0.f;
    m1aa[tid] = 0.f;
    float a_tm1 = 0.f, dm_tm1 = 0.f, b20 = 0.f, b21 = 0.f;   // tid 0 state
    if (tid == 0) { b20 = b2g[0]; b21 = b2g[1]; }
    int anyLocal = 0;

    // prologue prefetch (t = 0)
    float s1_c = 0.f, s1t_c = 0.f, xt_c = 0.f, xu_c = 0.f, xa0_c = 0.f, xa1_c = 0.f;
    float ap_c = 0.f, dm_c = 0.f, sdm_c = 1.f, sem_c = 0.f;
    {
        const float* rp = raw + (size_t)b * NCAT;
        if (tid < H2C) s1_c = NTL(rp[tid]);
        if (tid < HH) { s1t_c = NTL(rp[H2C + tid]); xt_c = NTL(xh[(size_t)b * HH + tid]); }
        xu_c = NTL(XU[(size_t)b * NU + tid]);
        if (wv == 0) { xa0_c = NTL(rp[H3C + lane]); xa1_c = NTL(rp[H3C + 64 + lane]); }
        if (tid == 0) { ap_c = apcur[b]; dm_c = dmcur[b]; }
    }
    __syncthreads();

    for (int t = 0; t < LL; ++t) {
        const int rowc = t * BB + b;
        const int rowN = (t < LL - 1 ? t + 1 : t) * BB + b;
        // issue next-step prefetch (row t+1 of xh still holds x: h[t] not yet written)
        float s1_n = 0.f, s1t_n = 0.f, xt_n = 0.f, xu_n = 0.f, xa0_n = 0.f, xa1_n = 0.f;
        float ap_n = 0.f, dm_n = 0.f, sdm_n = 0.f, sem_n = 0.f;
        {
            const float* rp = raw + (size_t)rowN * NCAT;
            if (tid < H2C) s1_n = NTL(rp[tid]);
            if (tid < HH) { s1t_n = NTL(rp[H2C + tid]); xt_n = NTL(xh[(size_t)rowN * HH + tid]); }
            xu_n = NTL(XU[(size_t)rowN * NU + tid]);
            if (wv == 0) { xa0_n = NTL(rp[H3C + lane]); xa1_n = NTL(rp[H3C + 64 + lane]); }
            if (tid == 0) { ap_n = apcur[rowN]; dm_n = dmcur[rowN];
                            sdm_n = dmcur[rowc]; sem_n = eosb[rowc]; }
        }

        // ---- P0: action logits from cached aa (wave 0); gate logic on tid 0
        if (wv == 0) {
            float v0 = fmaxf(xa0_c + m1aa[H2C + lane], 0.f);
            float v1 = fmaxf(xa1_c + m1aa[H2C + 64 + lane], 0.f);
            float l0 = v0 * w2l[lane * 2]     + v1 * w2l[(64 + lane) * 2];
            float l1 = v0 * w2l[lane * 2 + 1] + v1 * w2l[(64 + lane) * 2 + 1];
            #pragma unroll
            for (int o = 32; o; o >>= 1) { l0 += __shfl_down(l0, o); l1 += __shfl_down(l1, o); }
            if (lane == 0) {
                float p0 = fminf(expf(l0 + b20), 1000.f);
                float p1 = fminf(expf(l1 + b21), 1000.f);
                float act = (p0 <= p1) ? 1.f : 0.f;
                if (ap_c  > 0.f) act = 1.f;
                if (llm   > 0)   act = 1.f;
                if (sem_c > 0.f) act = 0.f;
                float both   = (1.f - ap_c) * dm_c * act * dm_tm1;
                float h_only = dm_tm1 * act * (ap_c + (1.f - ap_c) * (1.f - dm_c));
                float x_only = dm_c * (1.f - ap_c) * (1.f - act + act * (1.f - dm_tm1));
                float dmnew  = both + x_only + h_only;
                float a_out  = (sdm_c > 0.f) ? act : a_tm1;
                aseq[rowc] = a_out; dmseq[rowc] = dmnew;
                a_tm1 = a_out; dm_tm1 = dmnew;
                anyLocal |= (both > 0.f) ? 1 : 0;
                int cd;
                if (dm_c <= 0.f)       cd = 0;   // h kept (dm override)
                else if (both > 0.f)   cd = 3;   // full update
                else if (h_only > 0.f) cd = 0;   // h kept
                else if (x_only > 0.f) cd = 1;   // h = x_t
                else                   cd = 2;   // h = 0
                code_s = cd;
            }
        }
        __syncthreads();   // B1
        int cd = code_s;

        if (cd == 3) {
            // ---- m1 LN stats from cache
            if (tid < H2C) {
                float v = m1aa[tid];
                float s = v, q = v * v;
                #pragma unroll
                for (int o = 32; o; o >>= 1) { s += __shfl_down(s, o); q += __shfl_down(q, o); }
                if (lane == 0) { red[wv * 2] = s; red[wv * 2 + 1] = q; }
            }
            __syncthreads();   // B2
            if (tid < H2C) {
                float ss = 0.f, qs = 0.f;
                #pragma unroll
                for (int w8 = 0; w8 < 8; ++w8) { ss += red[w8 * 2]; qs += red[w8 * 2 + 1]; }
                float mean = ss * (1.f / 512.f);
                float var  = qs * (1.f / 512.f) - mean * mean;
                float inv  = 1.f / (sqrtf(var + EPSV) + EPSV);
                float s2 = g1v[tid] * ((m1aa[tid] - mean) * inv) + be1v[tid];
                float gate = hsg(s1_c + s2);
                if (tid < HH) z_s[tid] = gate;
                else          rh_s[tid - HH] = gate * h_s[tid - HH];
            }
            __syncthreads();   // B3
            // ---- m2 = rh @ U[:,512:768] via UT3 rows (contiguous), split-K by 2
            if (tid < H2C) {
                int c = tid & (HH - 1), half = tid >> 8;
                const float* urow = UT3 + (size_t)c * HH + half * 128;
                const float* rh = rh_s + half * 128;
                float a0 = 0.f, a1 = 0.f, a2 = 0.f, a3 = 0.f;
                #pragma unroll 4
                for (int k = 0; k < 128; k += 8) {
                    float4 u0 = *(const float4*)&urow[k];
                    float4 u1 = *(const float4*)&urow[k + 4];
                    float4 r0 = *(const float4*)&rh[k];
                    float4 r1 = *(const float4*)&rh[k + 4];
                    a0 = fmaf(u0.x, r0.x, a0); a1 = fmaf(u0.y, r0.y, a1);
                    a2 = fmaf(u0.z, r0.z, a2); a3 = fmaf(u0.w, r0.w, a3);
                    a0 = fmaf(u1.x, r1.x, a0); a1 = fmaf(u1.y, r1.y, a1);
                    a2 = fmaf(u1.z, r1.z, a2); a3 = fmaf(u1.w, r1.w, a3);
                }
                pm[tid] = (a0 + a1) + (a2 + a3);
            }
            __syncthreads();   // B4
            float m2v = 0.f;
            if (tid < HH) {
                m2v = pm[tid] + pm[tid + HH];
                float s = m2v, q = m2v * m2v;
                #pragma unroll
                for (int o = 32; o; o >>= 1) { s += __shfl_down(s, o); q += __shfl_down(q, o); }
                if (lane == 0) { red[wv * 2] = s; red[wv * 2 + 1] = q; }
            }
            __syncthreads();   // B5
            if (tid < HH) {
                float ss = 0.f, qs = 0.f;
                #pragma unroll
                for (int w4 = 0; w4 < 4; ++w4) { ss += red[w4 * 2]; qs += red[w4 * 2 + 1]; }
                float mean = ss * (1.f / 256.f);
                float var  = qs * (1.f / 256.f) - mean * mean;
                float inv  = 1.f / (sqrtf(var + EPSV) + EPSV);
                float ln2 = g2v[tid] * ((m2v - mean) * inv) + be2v[tid];
                float tc = tanhf(s1t_c + ln2);
                float zv = z_s[tid];
                float hc = zv * h_s[tid] + (1.f - zv) * tc;
                h_s[tid] = hc;
                xh[(size_t)rowc * HH + tid] = hc;
            }
            __syncthreads();   // B6 (new h visible)
            // ---- refresh cache: m1aa = h @ [U12 | Ua1] via UT12a rows (contiguous)
            {
                const float* urow = UT12a + (size_t)tid * HH;
                float a0 = 0.f, a1 = 0.f, a2 = 0.f, a3 = 0.f;
                #pragma unroll 4
                for (int k = 0; k < HH; k += 8) {
                    float4 u0 = *(const float4*)&urow[k];
                    float4 u1 = *(const float4*)&urow[k + 4];
                    float4 h0 = *(const float4*)&h_s[k];
                    float4 h1 = *(const float4*)&h_s[k + 4];
                    a0 = fmaf(u0.x, h0.x, a0); a1 = fmaf(u0.y, h0.y, a1);
                    a2 = fmaf(u0.z, h0.z, a2); a3 = fmaf(u0.w, h0.w, a3);
                    a0 = fmaf(u1.x, h1.x, a0); a1 = fmaf(u1.y, h1.y, a1);
                    a2 = fmaf(u1.z, h1.z, a2); a3 = fmaf(u1.w, h1.w, a3);
                }
                m1aa[tid] = (a0 + a1) + (a2 + a3);
            }
            __syncthreads();   // B7 (cache ready for next P0)
        } else {
            if (cd == 1) {            // h = x_t, cache = precomputed XU row
                if (tid < HH) h_s[tid] = xt_c;
                m1aa[tid] = xu_c;
            } else if (cd == 2) {     // h = 0
                if (tid < HH) h_s[tid] = 0.f;
                m1aa[tid] = 0.f;
            }
            __syncthreads();   // Bend
            if (tid < HH) xh[(size_t)rowc * HH + tid] = h_s[tid];
        }

        // rotate prefetch regs
        s1_c = s1_n; s1t_c = s1t_n; xt_c = xt_n; xu_c = xu_n;
        xa0_c = xa0_n; xa1_c = xa1_n;
        ap_c = ap_n; dm_c = dm_n; sdm_c = sdm_n; sem_c = sem_n;
    }
    if (tid == 0 && anyLocal) atomicOr(anyb, 1);
}

// ---------------------------------------------------------------- commit (vstep glue)
__global__ void commit_pass(float* __restrict__ apcur, const float* __restrict__ aseq,
                            float* __restrict__ dmcur, const float* __restrict__ dmseq,
                            const int* __restrict__ donep, int* __restrict__ donep1,
                            const int* __restrict__ anyb)
{
    int i = blockIdx.x * 256 + threadIdx.x;   // over MROWS
    int done = *donep;
    if (blockIdx.x == 0 && threadIdx.x == 0)
        *donep1 = done | ((*anyb == 0) ? 1 : 0);
    if (done || i >= MROWS) return;
    int t = i >> 7;
    apcur[i] = (t < LL - 1) ? aseq[i + BB] : 0.f;
    dmcur[i] = dmseq[i];
}

__global__ void write_out(const float* __restrict__ xh, float* __restrict__ outp) {
    int i = blockIdx.x * 256 + threadIdx.x;   // 32768 = B*H
    if (i >= BB * HH) return;
    int b = i >> 8, h = i & 255;
    outp[i] = xh[((size_t)(LL - 1) * BB + b) * HH + h];
}

// ---------------------------------------------------------------- launcher
static inline size_t alignUp(size_t v) { return (v + 255) & ~(size_t)255; }

extern "C" void kernel_launch(void* const* d_in, const int* in_sizes, int n_in,
                              void* d_out, int out_size, void* d_ws, size_t ws_size,
                              hipStream_t stream) {
    (void)in_sizes; (void)n_in; (void)out_size; (void)ws_size;
    const float* x     = (const float*)d_in[0];
    const float* mask  = (const float*)d_in[1];
    const float* W_emb = (const float*)d_in[3];
    const float* b_emb = (const float*)d_in[4];
    const float* W     = (const float*)d_in[5];
    const float* U     = (const float*)d_in[6];
    const float* bvec  = (const float*)d_in[7];
    const float* Wa1   = (const float*)d_in[8];
    const float* Ua1   = (const float*)d_in[9];
    const float* ba1   = (const float*)d_in[10];
    const float* W2    = (const float*)d_in[11];
    const float* b2    = (const float*)d_in[12];
    const float* gam   = (const float*)d_in[13];
    const float* bet   = (const float*)d_in[14];
    float* outp = (float*)d_out;

    // workspace budget: raw 117.4 + XU 83.9 + xh 33.5 + weights ~2.8 MB = ~238 MB
    char* ws = (char*)d_ws;
    size_t off = 0;
    auto take = [&](size_t bytes) { char* p = ws + off; off = alignUp(off + bytes); return p; };
    float* raw  = (float*)take((size_t)MROWS * NCAT * 4);     // 117.4 MB
    float* XU   = (float*)take((size_t)MROWS * NU * 4);       // 83.9 MB
    float* xh   = (float*)take((size_t)MROWS * HH * 4);       // 33.5 MB (x in / h out)
    u16* WcT_hi = (u16*)take((size_t)NCAT * HH * 2);
    u16* WcT_lo = (u16*)take((size_t)NCAT * HH * 2);
    u16* UcT_hi = (u16*)take((size_t)NU * HH * 2);
    u16* UcT_lo = (u16*)take((size_t)NU * HH * 2);
    u16* WeT_hi = (u16*)take((size_t)HH * DD * 2);
    u16* WeT_lo = (u16*)take((size_t)HH * DD * 2);
    float* UT12a = (float*)take((size_t)NU * HH * 4);         // 0.66 MB
    float* UT3   = (float*)take((size_t)HH * HH * 4);         // 0.26 MB
    float* apcur = (float*)take((size_t)MROWS * 4);
    float* dmcur = (float*)take((size_t)MROWS * 4);
    float* eosb  = (float*)take((size_t)MROWS * 4);
    float* aseq  = (float*)take((size_t)MROWS * 4);
    float* dmseq = (float*)take((size_t)MROWS * 4);
    float* bcat  = (float*)take((size_t)NCAT * 4);
    int* flags   = (int*)take(64);
    int* done = flags;        // done[0..3]
    int* anyb = flags + 4;    // anyb[0..3]

    init_flags<<<1, 64, 0, stream>>>(flags);
    build_bcat<<<4, 256, 0, stream>>>(bvec, ba1, bcat);
    conv_wcatT<<<(NCAT * HH + 255) / 256, 256, 0, stream>>>(W, Wa1, WcT_hi, WcT_lo);
    conv_ucatT<<<(NU * HH + 255) / 256, 256, 0, stream>>>(U, Ua1, UcT_hi, UcT_lo);
    conv_utT<<<((NU + HH) * HH + 255) / 256, 256, 0, stream>>>(U, Ua1, UT12a, UT3);
    conv_wembT<<<(HH * DD + 255) / 256, 256, 0, stream>>>(W_emb, WeT_hi, WeT_lo);
    init_seq<<<MROWS / 256, 256, 0, stream>>>(mask, apcur, dmcur, eosb);

    // embed: xh[(t,b)] = x[(b,l)] @ W_emb + b_emb   (A = f32 x, remap to [L][B])
    gemm_af32<<<dim3(HH / 128, MROWS / 128), 256, 0, stream>>>(
        x, WeT_hi, WeT_lo, xh, HH, DD, b_emb, 1, nullptr);

    for (int p = 0; p < 4; ++p) {
        const int* skip = (p == 1 || p == 2) ? &done[p] : nullptr;
        gemm_af32<<<dim3(NCAT / 128, MROWS / 128), 256, 0, stream>>>(
            xh, WcT_hi, WcT_lo, raw, NCAT, HH, nullptr, 0, skip);
        gemm_af32<<<dim3(NU / 128, MROWS / 128), 256, 0, stream>>>(
            xh, UcT_hi, UcT_lo, XU, NU, HH, nullptr, 0, skip);
        ln_rows<<<MROWS / 4, 256, 0, stream>>>(raw, bcat, gam, bet, skip);
        scan_sparse<<<BB, 640, 0, stream>>>(raw, xh, XU, apcur, dmcur, eosb,
                                            aseq, dmseq, UT12a, UT3, W2, b2, gam, bet,
                                            (p == 3) ? 1 : 0, &anyb[p], skip);
        if (p < 3)
            commit_pass<<<MROWS / 256, 256, 0, stream>>>(
                apcur, aseq, dmcur, dmseq, &done[p], &done[p + 1], &anyb[p]);
    }
    write_out<<<(BB * HH) / 256, 256, 0, stream>>>(xh, outp);
}